// Round 4
// baseline (241.349 us; speedup 1.0000x reference)
//
#include <hip/hip_runtime.h>
#include <stdint.h>

// UKF (affine motion => exact Kalman filter). Inputs fp32, outputs fp32.
//
// R5: octet groups -> 128B-contiguous flush stores (1x write amp).
// R6: phase-staggered flushes, M=K*S=Pxz identity, v_rcp.
// R7: LDS temporal staging (killed reg-staging hazards + selects).
// R8: all-lane flush; prefetch (defeated by compiler: VGPR stayed 52).
// R9 (this round): REDUNDANCY 16 -> 2x MEMORY CONCURRENCY.
//   Diagnosis: dur == hbm_bytes / ~1.9 TB/s across ALL of R5-R8 despite
//   ~90 instr/sub of issue cuts; WRITE amp already ~1.0. Little's law:
//   8 waves/CU x 3KB stores per 3.8us sub at ~0.8us store lifetime
//   = ~6KB outstanding/CU = 1.9 TB/s. We are CONCURRENCY-starved, and
//   occupancy is grid-capped (B*8/64 = 2 waves/SIMD).
//   => 16 lanes per b: 4096 waves; LDS re-tiled to 2-step windows x 16
//   slots = 34.1KB/block so 4 blocks/CU fit -> 16 waves/CU (4/SIMD).
//   Flush invariant kept: 16 lanes x 8B = 128B contiguous per instr;
//   one of the wave's 4 groups flushes every 4th sub (stagger mod 16).
//   Cost: total issue doubles (VALU had 66% headroom).

static constexpr float DTc  = 0.1f;
static constexpr float HDT2 = 0.5f * DTc * DTc;
static constexpr int SSd = 33;                   // dwords per window slot (16 rows x 2 + 1)
static constexpr int GS  = 16 * SSd + 5;         // 533 dwords per group (odd: bank spread)
static constexpr int LDS_BYTES = 16 * GS * 4;    // 34112 B per block

__global__ __launch_bounds__(256, 4) void ukf_r9(
    const float* __restrict__ meas,   // (B, 2, S)
    const float* __restrict__ stin,   // (B, 4)
    const float* __restrict__ covin,  // (B, 4, 4)
    const float* __restrict__ ctrl,   // (B, S, 2)
    const float* __restrict__ Qp,     // (4,4)
    const float* __restrict__ Rp,     // (2,2)
    float* __restrict__ out,          // preds (B,2,S) | states (B,4,S) | covs (B,4,4,S)
    int B, int S)
{
    extern __shared__ float lds[];

    const int tid  = blockIdx.x * 256 + threadIdx.x;
    const int b    = tid >> 4;             // 16 lanes per batch element
    const int myj  = threadIdx.x & 15;     // window index / lane role in group
    if (b >= B) return;
    const int lane = threadIdx.x & 63;
    const int rrow = lane >> 4;            // 0..3 : row-cluster within wave
    const int wb4  = b & ~3;               // wave's base batch element
    const int g    = threadIdx.x >> 4;     // block-level group 0..15
    const int wg4  = (threadIdx.x >> 6) << 2;  // wave's first block-group
    const int phase = b & 15;              // capture/flush phase stagger

    float* ldsg = lds + g * GS;            // this group's staging region

    float4 s4 = *reinterpret_cast<const float4*>(stin + (size_t)b * 4);
    float x0 = s4.x, x1 = s4.y, x2 = s4.z, x3 = s4.w;

    float p00, p01, p02, p03, p11, p12, p13, p22, p23, p33;
    {
        const float4* pc = reinterpret_cast<const float4*>(covin + (size_t)b * 16);
        float4 r0 = pc[0], r1 = pc[1], r2 = pc[2], r3 = pc[3];
        p00 = r0.x; p01 = r0.y; p02 = r0.z; p03 = r0.w;
        p11 = r1.y; p12 = r1.z; p13 = r1.w; p22 = r2.z; p23 = r2.w; p33 = r3.w;
    }
    float q00, q01, q02, q03, q11, q12, q13, q22, q23, q33;
    {
        const float4* pq = reinterpret_cast<const float4*>(Qp);
        float4 r0 = pq[0], r1 = pq[1], r2 = pq[2], r3 = pq[3];
        q00 = r0.x; q01 = r0.y; q02 = r0.z; q03 = r0.w;
        q11 = r1.y; q12 = r1.z; q13 = r1.w; q22 = r2.z; q23 = r2.w; q33 = r3.w;
    }
    float R00, R01, R10, R11;
    {
        float4 r = *reinterpret_cast<const float4*>(Rp);
        R00 = r.x; R01 = r.y; R10 = r.z; R11 = r.w;
    }

    const float2* pm0 = reinterpret_cast<const float2*>(meas + (size_t)b * 2 * S);
    const float2* pm1 = reinterpret_cast<const float2*>(meas + (size_t)b * 2 * S + S);
    const float4* pu  = reinterpret_cast<const float4*>(ctrl + (size_t)b * S * 2);

    const int NS2 = S / 2;                 // 2-step subs (50 for S=100)

    // ---- per-lane flush constants (6 passes; item = row x window) ----
    // out rows: 0,1 = preds; 2..5 = states; 6..21 = covs (4x4 via tri map)
    int      ldsoff[6];    // byte offset within flushing group's region
    uint32_t rbase[6];     // dword offset in out for batch wb4, row, +2*myj
    uint32_t mult[6];      // per-batch row-region stride (rr*S dwords)
    bool     act[6];
    {
        const int map16[16] = {0,1,2,3, 1,4,5,6, 2,5,7,8, 3,6,8,9};
#pragma unroll
        for (int p = 0; p < 6; ++p) {
            const int row = p * 4 + rrow;
            act[p] = (row < 22);
            const int lrow = (row < 6) ? row : (row < 22 ? 6 + map16[row - 6] : 0);
            ldsoff[p] = (myj * SSd + lrow * 2) * 4;
            int rr, rowIn; uint32_t base0;
            if (row < 2)      { rr = 2;  rowIn = row;                    base0 = 0u; }
            else if (row < 6) { rr = 4;  rowIn = row - 2;                base0 = (uint32_t)B * 2u * (uint32_t)S; }
            else              { rr = 16; rowIn = (row < 22 ? row - 6 : 0); base0 = (uint32_t)B * 6u * (uint32_t)S; }
            mult[p]  = (uint32_t)(rr * S);
            rbase[p] = base0 + (uint32_t)wb4 * mult[p] + (uint32_t)(rowIn * S) + (uint32_t)(2 * myj);
        }
    }

    float2 m0 = pm0[0], m1 = pm1[0];
    float4 u01 = pu[0];

    for (int sub = 0; sub < NS2 + 15; ++sub) {
        float2 nm0 = make_float2(0, 0), nm1 = nm0;
        float4 nu = make_float4(0, 0, 0, 0);
        if (sub + 1 < NS2) {
            nm0 = pm0[sub + 1];
            nm1 = pm1[sub + 1];
            nu  = pu[sub + 1];
        }

        if (sub < NS2) {
            const float zb0[2] = { m0.x, m0.y };
            const float zb1[2] = { m1.x, m1.y };
            const float uxb[2] = { u01.x, u01.z };
            const float uyb[2] = { u01.y, u01.w };

            float* cap = ldsg + ((sub + phase) & 15) * SSd;

#pragma unroll
            for (int k = 0; k < 2; ++k) {
                const float ux = uxb[k], uy = uyb[k];

                const float xp0 = x0 + DTc * x2 + HDT2 * ux;
                const float xp1 = x1 + DTc * x3 + HDT2 * uy;
                const float xp2 = x2 + DTc * ux;
                const float xp3 = x3 + DTc * uy;

                const float FP00 = p00 + DTc * p02, FP01 = p01 + DTc * p12;
                const float FP02 = p02 + DTc * p22, FP03 = p03 + DTc * p23;
                const float FP11 = p11 + DTc * p13, FP12 = p12 + DTc * p23;
                const float FP13 = p13 + DTc * p33;

                const float a00 = FP00 + DTc * FP02, a01 = FP01 + DTc * FP03;
                const float a02 = FP02, a03 = FP03;
                const float a11 = FP11 + DTc * FP13, a12 = FP12, a13 = FP13;
                const float a22 = p22, a23 = p23, a33 = p33;

                const float s00 = a00 + R00, s01 = a01 + R01;
                const float s10 = a01 + R10, s11 = a11 + R11;
                const float rdet = __builtin_amdgcn_rcpf(s00 * s11 - s01 * s10);
                const float i00 =  s11 * rdet, i01 = -s01 * rdet;
                const float i10 = -s10 * rdet, i11 =  s00 * rdet;

                const float K00 = a00*i00 + a01*i10, K01 = a00*i01 + a01*i11;
                const float K10 = a01*i00 + a11*i10, K11 = a01*i01 + a11*i11;
                const float K20 = a02*i00 + a12*i10, K21 = a02*i01 + a12*i11;
                const float K30 = a03*i00 + a13*i10, K31 = a03*i01 + a13*i11;

                const float in0 = zb0[k] - xp0, in1 = zb1[k] - xp1;
                const float xn0 = xp0 + K00*in0 + K01*in1;
                const float xn1 = xp1 + K10*in0 + K11*in1;
                const float xn2 = xp2 + K20*in0 + K21*in1;
                const float xn3 = xp3 + K30*in0 + K31*in1;

                // M = K*S = Pxz = a[:,0:2] -> P = a + Q - Pxz*K^T
                p00 = (a00 + q00) - a00*K00 - a01*K01;
                p01 = (a01 + q01) - a00*K10 - a01*K11;
                p02 = (a02 + q02) - a00*K20 - a01*K21;
                p03 = (a03 + q03) - a00*K30 - a01*K31;
                p11 = (a11 + q11) - a01*K10 - a11*K11;
                p12 = (a12 + q12) - a01*K20 - a11*K21;
                p13 = (a13 + q13) - a01*K30 - a11*K31;
                p22 = (a22 + q22) - a02*K20 - a12*K21;
                p23 = (a23 + q23) - a02*K30 - a12*K31;
                p33 = (a33 + q33) - a03*K30 - a13*K31;

                x0 = xn0; x1 = xn1; x2 = xn2; x3 = xn3;

                // capture: lane 0 of each group writes this step into the
                // slot; [row][k] pairs fuse to ds_write2_b32.
                if (myj == 0) {
                    cap[ 0*2 + k] = xp0;  cap[ 1*2 + k] = xp1;
                    cap[ 2*2 + k] = xn0;  cap[ 3*2 + k] = xn1;
                    cap[ 4*2 + k] = xn2;  cap[ 5*2 + k] = xn3;
                    cap[ 6*2 + k] = p00;  cap[ 7*2 + k] = p01;
                    cap[ 8*2 + k] = p02;  cap[ 9*2 + k] = p03;
                    cap[10*2 + k] = p11;  cap[11*2 + k] = p12;
                    cap[12*2 + k] = p13;  cap[13*2 + k] = p22;
                    cap[14*2 + k] = p23;  cap[15*2 + k] = p33;
                }
            }
        }

        // ---- all-lane flush: group gfi of this wave iff gfi < 4 ----
        // lane l: row-cluster rrow = l>>4, window myj = l&15 (slot == myj at
        // flush). 16-lane clusters store 8B each = 128B contiguous.
        {
            const int gfi = (15 - sub - (wb4 & 15)) & 15;
            if (gfi < 4) {
                const float* fsrc = lds + (size_t)(wg4 + gfi) * GS;
                const int w = sub - 15 + myj;
                const bool wok = (w >= 0) && (w < NS2);
                const int dcol = (sub - 15) * 2;
#pragma unroll
                for (int p = 0; p < 6; ++p) {
                    const float2 v = *reinterpret_cast<const float2*>(
                        reinterpret_cast<const char*>(fsrc) + ldsoff[p]);
                    if (wok && act[p]) {
                        const int off = (int)rbase[p] + gfi * (int)mult[p] + dcol;
                        *reinterpret_cast<float2*>(out + off) = v;
                    }
                }
            }
        }

        m0 = nm0; m1 = nm1; u01 = nu;
    }
}

extern "C" void kernel_launch(void* const* d_in, const int* in_sizes, int n_in,
                              void* d_out, int out_size, void* d_ws, size_t ws_size,
                              hipStream_t stream) {
    // Identify inputs by element count (order-robust):
    int iR = -1, iQ = -1, iMeas = -1, iCtrl = -1, iState = -1, iCov = -1;
    for (int i = 0; i < n_in; i++) {
        if (in_sizes[i] == 4 && iR < 0) iR = i;
        else if (in_sizes[i] == 16 && iQ < 0) iQ = i;
    }
    for (int i = 0; i < n_in && iMeas < 0; i++) {
        if (i == iR || i == iQ) continue;
        for (int j = i + 1; j < n_in; j++) {
            if (j == iR || j == iQ) continue;
            if (in_sizes[i] == in_sizes[j]) { iMeas = i; iCtrl = j; break; }
        }
    }
    int rem[2], nrem = 0;
    for (int i = 0; i < n_in && nrem < 2; i++) {
        if (i == iR || i == iQ || i == iMeas || i == iCtrl) continue;
        rem[nrem++] = i;
    }
    if (in_sizes[rem[0]] > in_sizes[rem[1]]) { iCov = rem[0]; iState = rem[1]; }
    else                                     { iCov = rem[1]; iState = rem[0]; }

    const float* meas  = (const float*)d_in[iMeas];
    const float* stin  = (const float*)d_in[iState];
    const float* covin = (const float*)d_in[iCov];
    const float* ctrl  = (const float*)d_in[iCtrl];
    const float* Qp    = (const float*)d_in[iQ];
    const float* Rp    = (const float*)d_in[iR];
    float* out = (float*)d_out;

    const int B = in_sizes[iState] / 4;
    const int S = in_sizes[iMeas] / (2 * B);

    // 16 threads per batch element, 256-thread blocks, 34112 B dynamic LDS
    const int total = B * 16;
    ukf_r9<<<dim3((total + 255) / 256), dim3(256), LDS_BYTES, stream>>>(
        meas, stin, covin, ctrl, Qp, Rp, out, B, S);
}